// Round 1
// 83.602 us; speedup vs baseline: 1.0228x; 1.0228x over previous
//
#include <hip/hip_runtime.h>

// Problem constants (match reference)
#define B_ 2
#define N_ 1024
#define M_ 1024
#define H_ 128
// SCALE = 1 / 128^0.4
#define SCALE_F 0.14358729f

// Fully fused kernel — NO workspace use (the previous 2-kernel version passed
// p[] through d_ws, which forced a 256 MiB workspace re-poison fill (~2x41 us)
// inside the timed region; that fill WAS the measured 85 us).
//
// Math note (same as before): logits = SCALE*(qs[n] + ks[m]); qs[n] and the
// bias-sum are constant over the softmax axis m and cancel exactly, so
// queries/b are never needed. p[b,m] = softmax_m(SCALE * keys[b,m,:]·colsum(W)),
// out[b,n,m] = p[b,m] * values[b,n].
//
// Grid: 256 blocks x 1024 threads. Block i: batch b = i>>7, rows n in
// [ (i&127)*8, +8 ). Each block redundantly recomputes p[b,:] (keys row reads
// are L2-resident: 128 blocks/batch x 512 KB = 64 MB L2 traffic per batch),
// then writes its 32 KB output slice. Redundant recompute is what lets us
// avoid any inter-kernel global scratch.
__global__ void __launch_bounds__(1024) fused_kernel(
    const float* __restrict__ keys,   // [B, M, H]
    const float* __restrict__ values, // [B, N] (flattened [B,N,1,1])
    const float* __restrict__ W,      // [H, H] row-major
    float4* __restrict__ out)         // [B, N, M] as float4
{
    const int blk   = blockIdx.x;         // 0..255
    const int b     = blk >> 7;           // 0..1
    const int nbase = (blk & 127) << 3;   // 8 rows per block
    const int m     = threadIdx.x;        // 0..1023

    __shared__ float wpart[8][H_];
    __shared__ float wsum[H_];
    __shared__ float p_lds[M_];
    __shared__ float red[16];
    __shared__ float bc[2];

    // ---- colsum over rows o of W, parallelized over all 1024 threads ----
    {
        const int col = m & (H_ - 1);     // 0..127
        const int grp = m >> 7;           // 0..7
        float s = 0.f;
        #pragma unroll
        for (int i = 0; i < 16; ++i)
            s += W[(grp * 16 + i) * H_ + col];
        wpart[grp][col] = s;
    }
    __syncthreads();
    if (m < H_) {
        float t = 0.f;
        #pragma unroll
        for (int g = 0; g < 8; ++g) t += wpart[g][m];
        wsum[m] = t;
    }
    __syncthreads();

    // ---- logit = SCALE * dot(keys[b,m,:], wsum) ----
    const float4* krow = (const float4*)(keys + ((size_t)b * M_ + m) * H_);
    const float4* w4   = (const float4*)wsum;   // same-address per iter -> LDS broadcast
    float acc = 0.f;
    #pragma unroll
    for (int i = 0; i < H_ / 4; ++i) {
        float4 k4 = krow[i];
        float4 ww = w4[i];
        acc = fmaf(k4.x, ww.x, acc);
        acc = fmaf(k4.y, ww.y, acc);
        acc = fmaf(k4.z, ww.z, acc);
        acc = fmaf(k4.w, ww.w, acc);
    }
    const float logit = SCALE_F * acc;

    const int lane = m & 63;
    const int wid  = m >> 6;      // 16 waves

    // ---- block max ----
    float v = logit;
    #pragma unroll
    for (int off = 32; off > 0; off >>= 1) v = fmaxf(v, __shfl_down(v, off));
    if (lane == 0) red[wid] = v;
    __syncthreads();
    if (wid == 0) {
        float t = (lane < 16) ? red[lane] : -3.4e38f;
        #pragma unroll
        for (int off = 8; off > 0; off >>= 1) t = fmaxf(t, __shfl_down(t, off));
        if (lane == 0) bc[0] = t;
    }
    __syncthreads();              // bc[0] visible; red free to reuse after this
    const float gmax = bc[0];
    const float e = __expf(logit - gmax);
    p_lds[m] = e;                 // unnormalized; fold 1/sum into values scalar

    // ---- block sum ----
    v = e;
    #pragma unroll
    for (int off = 32; off > 0; off >>= 1) v += __shfl_down(v, off);
    if (lane == 0) red[wid] = v;
    __syncthreads();
    if (wid == 0) {
        float t = (lane < 16) ? red[lane] : 0.f;
        #pragma unroll
        for (int off = 8; off > 0; off >>= 1) t += __shfl_down(t, off);
        if (lane == 0) bc[1] = 1.0f / t;
    }
    __syncthreads();              // bc[1] + p_lds visible
    const float inv = bc[1];

    // ---- write 8 rows: 2 passes of 4 rows (1024 threads = 4 x 256 float4) ----
    const float4* p4 = (const float4*)p_lds;
    const int m4 = m & 255;
    const int rr = m >> 8;        // 0..3
    #pragma unroll
    for (int pass = 0; pass < 2; ++pass) {
        const int n  = nbase + pass * 4 + rr;
        const float vv = values[(b << 10) + n] * inv;
        const float4 pv = p4[m4];
        float4 o;
        o.x = pv.x * vv; o.y = pv.y * vv; o.z = pv.z * vv; o.w = pv.w * vv;
        out[(((size_t)(b << 10) + n) << 8) + m4] = o;
    }
}

extern "C" void kernel_launch(void* const* d_in, const int* in_sizes, int n_in,
                              void* d_out, int out_size, void* d_ws, size_t ws_size,
                              hipStream_t stream) {
    // inputs: 0=queries (unused!), 1=keys, 2=values, 3=W, 4=b (cancels in softmax)
    const float* keys   = (const float*)d_in[1];
    const float* values = (const float*)d_in[2];
    const float* W      = (const float*)d_in[3];
    float4* out = (float4*)d_out;

    // d_ws deliberately untouched: using it triggers a 256 MiB poison fill in
    // the timed region (~82 us), dwarfing the actual compute (<10 us).
    fused_kernel<<<256, 1024, 0, stream>>>(keys, values, W, out);
}